// Round 1
// baseline (760.134 us; speedup 1.0000x reference)
//
#include <hip/hip_runtime.h>
#include <cstdint>
#include <cstddef>

#define NNODES 10000
#define NEDGES 320000
#define NTOT   (NEDGES + NNODES)

// ---------- helpers ----------
__device__ __forceinline__ unsigned fkey(float f) {
  unsigned u = __float_as_uint(f);
  return (u & 0x80000000u) ? ~u : (u | 0x80000000u);
}
__device__ __forceinline__ float fdec(unsigned k) {
  unsigned u = (k & 0x80000000u) ? (k ^ 0x80000000u) : ~k;
  return __uint_as_float(u);
}
__device__ __forceinline__ float lrelu(float x) { return x > 0.f ? x : 0.2f * x; }

// ---------- GEMM: C[N,M] = A[N,K] @ B[K,M] ----------
__global__ __launch_bounds__(256) void gemm_kernel(
    const float* __restrict__ A, const float* __restrict__ B, float* __restrict__ C,
    int N, int K, int M) {
  __shared__ float As[8][68];
  __shared__ float Bs[8][68];
  int tid = threadIdx.x;
  int n0 = blockIdx.x * 64;
  int m0 = blockIdx.y * 64;
  int tx = tid & 15, ty = tid >> 4;
  float acc[4][4] = {{0.f}};
  int an = tid >> 2;
  int ak = (tid & 3) << 1;
  int bk = tid >> 5;
  int bm = (tid & 31) << 1;
  const float* Arow = A + (size_t)(n0 + an) * K;
  bool avalid = (n0 + an) < N;
  for (int k0 = 0; k0 < K; k0 += 8) {
    float a0 = 0.f, a1 = 0.f;
    if (avalid) { a0 = Arow[k0 + ak]; a1 = Arow[k0 + ak + 1]; }
    As[ak][an] = a0; As[ak + 1][an] = a1;
    const float* Bp = B + (size_t)(k0 + bk) * M + m0 + bm;
    Bs[bk][bm] = Bp[0]; Bs[bk][bm + 1] = Bp[1];
    __syncthreads();
#pragma unroll
    for (int kk = 0; kk < 8; ++kk) {
      float4 a4 = *(const float4*)&As[kk][ty << 2];
      float4 b4 = *(const float4*)&Bs[kk][tx << 2];
      float av[4] = {a4.x, a4.y, a4.z, a4.w};
      float bv[4] = {b4.x, b4.y, b4.z, b4.w};
#pragma unroll
      for (int i = 0; i < 4; ++i)
#pragma unroll
        for (int j = 0; j < 4; ++j)
          acc[i][j] = fmaf(av[i], bv[j], acc[i][j]);
    }
    __syncthreads();
  }
#pragma unroll
  for (int i = 0; i < 4; ++i) {
    int n = n0 + (ty << 2) + i;
    if (n < N) {
      float4 o = make_float4(acc[i][0], acc[i][1], acc[i][2], acc[i][3]);
      *(float4*)&C[(size_t)n * M + m0 + (tx << 2)] = o;
    }
  }
}

// ---------- attention coefficients: a_s[n,h]=dot(h[n,h,:],att_src[h,:]) ----------
template <int H>
__global__ void att_kernel(const float* __restrict__ hbuf, const float* __restrict__ atts,
                           const float* __restrict__ attd, float* __restrict__ a_s,
                           float* __restrict__ a_d, int N) {
  int n = blockIdx.x;
  int w = threadIdx.x >> 6;
  int c = threadIdx.x & 63;
  float v = hbuf[(size_t)n * (H * 64) + w * 64 + c];
  float ps = v * atts[w * 64 + c];
  float pd = v * attd[w * 64 + c];
#pragma unroll
  for (int off = 32; off; off >>= 1) {
    ps += __shfl_xor(ps, off);
    pd += __shfl_xor(pd, off);
  }
  if (c == 0) { a_s[n * H + w] = ps; a_d[n * H + w] = pd; }
}

// ---------- init ----------
__global__ void init_ms_kernel(unsigned* __restrict__ mkey, float* __restrict__ ssum, int n) {
  int i = blockIdx.x * 256 + threadIdx.x;
  if (i < n) { mkey[i] = 0u; ssum[i] = 0.f; }
}
__global__ void init_counts_kernel(int* __restrict__ counts, int N) {
  int i = blockIdx.x * 256 + threadIdx.x;
  if (i < N) counts[i] = 1;  // self loop
}
__global__ void hist_kernel(const int* __restrict__ ei, int* __restrict__ counts) {
  int e = blockIdx.x * 256 + threadIdx.x;
  if (e < NEDGES) atomicAdd(&counts[ei[NEDGES + e]], 1);
}

// single-block scan over counts -> row_ptr (exclusive), cursor copy
__global__ void scan_kernel(const int* __restrict__ counts, int* __restrict__ row_ptr,
                            int* __restrict__ cursor, int N) {
  __shared__ int part[256];
  int t = threadIdx.x;
  int chunk = (N + 255) >> 8;
  int base = t * chunk;
  int s = 0;
  for (int i = 0; i < chunk; ++i) {
    int idx = base + i;
    if (idx < N) s += counts[idx];
  }
  part[t] = s;
  __syncthreads();
  for (int off = 1; off < 256; off <<= 1) {
    int v = (t >= off) ? part[t - off] : 0;
    __syncthreads();
    part[t] += v;
    __syncthreads();
  }
  int run = part[t] - s;  // exclusive prefix
  for (int i = 0; i < chunk; ++i) {
    int idx = base + i;
    if (idx < N) {
      row_ptr[idx] = run;
      cursor[idx] = run;
      run += counts[idx];
    }
  }
  if (t == 255) row_ptr[N] = part[255];
}

__global__ void scatter_kernel(const int* __restrict__ ei, int* __restrict__ cursor,
                               int* __restrict__ srcs) {
  int e = blockIdx.x * 256 + threadIdx.x;
  if (e < NEDGES) {
    int s = ei[e], d = ei[NEDGES + e];
    srcs[atomicAdd(&cursor[d], 1)] = s;
  } else if (e < NTOT) {
    int nn = e - NEDGES;
    srcs[atomicAdd(&cursor[nn], 1)] = nn;
  }
}

// ---------- edge passes: segment max, then exp-sum ----------
template <int H>
__global__ void edge_max_kernel(const int* __restrict__ ei, const float* __restrict__ a_s,
                                const float* __restrict__ a_d, unsigned* __restrict__ mkey) {
  int e = blockIdx.x * 256 + threadIdx.x;
  if (e >= NTOT) return;
  int s, d;
  if (e < NEDGES) { s = ei[e]; d = ei[NEDGES + e]; }
  else { s = d = e - NEDGES; }
#pragma unroll
  for (int h = 0; h < H; ++h) {
    float l = lrelu(a_s[s * H + h] + a_d[d * H + h]);
    atomicMax(&mkey[d * H + h], fkey(l));
  }
}

template <int H>
__global__ void edge_sum_kernel(const int* __restrict__ ei, const float* __restrict__ a_s,
                                const float* __restrict__ a_d, const unsigned* __restrict__ mkey,
                                float* __restrict__ ssum) {
  int e = blockIdx.x * 256 + threadIdx.x;
  if (e >= NTOT) return;
  int s, d;
  if (e < NEDGES) { s = ei[e]; d = ei[NEDGES + e]; }
  else { s = d = e - NEDGES; }
#pragma unroll
  for (int h = 0; h < H; ++h) {
    float l = lrelu(a_s[s * H + h] + a_d[d * H + h]);
    atomicAdd(&ssum[d * H + h], __expf(l - fdec(mkey[d * H + h])));
  }
}

// ---------- aggregation, layers 0/1 (H=4, C=64) + bias+ELU+BN ----------
__global__ __launch_bounds__(256) void aggregate_kernel(
    const float* __restrict__ hbuf, const float* __restrict__ a_s, const float* __restrict__ a_d,
    const unsigned* __restrict__ mkey, const float* __restrict__ ssum,
    const int* __restrict__ row_ptr, const int* __restrict__ srcs,
    const float* __restrict__ bias, const float* __restrict__ gam, const float* __restrict__ bet,
    const float* __restrict__ rmean, const float* __restrict__ rvar,
    float* __restrict__ xout, int N) {
  int n = blockIdx.x;
  int hh = threadIdx.x >> 6;
  int c = threadIdx.x & 63;
  float adn = a_d[n * 4 + hh];
  float mnh = fdec(mkey[n * 4 + hh]);
  float inv = 1.0f / (ssum[n * 4 + hh] + 1e-16f);
  float acc = 0.f;
  int je = row_ptr[n + 1];
  for (int j = row_ptr[n]; j < je; ++j) {
    int s = srcs[j];
    float l = lrelu(a_s[s * 4 + hh] + adn);
    float alpha = __expf(l - mnh) * inv;
    acc = fmaf(alpha, hbuf[(size_t)s * 256 + hh * 64 + c], acc);
  }
  int col = hh * 64 + c;
  float v = acc + bias[col];
  v = v > 0.f ? v : (__expf(v) - 1.f);  // ELU
  v = fmaf(gam[col] * (v - rmean[col]), rsqrtf(rvar[col] + 1e-5f), bet[col]);
  xout[(size_t)n * 256 + col] = v;
}

// ---------- aggregation layer 2 (H=1, C=64) + bias + log_softmax ----------
__global__ __launch_bounds__(256) void aggregate2_kernel(
    const float* __restrict__ hbuf, const float* __restrict__ a_s, const float* __restrict__ a_d,
    const unsigned* __restrict__ mkey, const float* __restrict__ ssum,
    const int* __restrict__ row_ptr, const int* __restrict__ srcs,
    const float* __restrict__ bias, float* __restrict__ out, int N) {
  int n = blockIdx.x * 4 + (threadIdx.x >> 6);
  int c = threadIdx.x & 63;
  if (n >= N) return;
  float adn = a_d[n];
  float mnh = fdec(mkey[n]);
  float inv = 1.0f / (ssum[n] + 1e-16f);
  float acc = 0.f;
  int je = row_ptr[n + 1];
  for (int j = row_ptr[n]; j < je; ++j) {
    int s = srcs[j];
    float alpha = __expf(lrelu(a_s[s] + adn) - mnh) * inv;
    acc = fmaf(alpha, hbuf[(size_t)s * 64 + c], acc);
  }
  float v = acc + bias[c];
  float mx = v;
#pragma unroll
  for (int off = 32; off; off >>= 1) mx = fmaxf(mx, __shfl_xor(mx, off));
  float ex = __expf(v - mx);
#pragma unroll
  for (int off = 32; off; off >>= 1) ex += __shfl_xor(ex, off);
  out[(size_t)n * 64 + c] = (v - mx) - logf(ex);
}

// ---------- host ----------
extern "C" void kernel_launch(void* const* d_in, const int* in_sizes, int n_in,
                              void* d_out, int out_size, void* d_ws, size_t ws_size,
                              hipStream_t stream) {
  const float* x = (const float*)d_in[0];
  const int* ei = (const int*)d_in[1];
  const float* W0 = (const float*)d_in[2];
  const float* as0 = (const float*)d_in[3];
  const float* ad0 = (const float*)d_in[4];
  const float* b0 = (const float*)d_in[5];
  const float* g0p = (const float*)d_in[6];
  const float* be0 = (const float*)d_in[7];
  const float* m0p = (const float*)d_in[8];
  const float* v0p = (const float*)d_in[9];
  const float* W1 = (const float*)d_in[10];
  const float* as1 = (const float*)d_in[11];
  const float* ad1 = (const float*)d_in[12];
  const float* b1 = (const float*)d_in[13];
  const float* g1p = (const float*)d_in[14];
  const float* be1 = (const float*)d_in[15];
  const float* m1p = (const float*)d_in[16];
  const float* v1p = (const float*)d_in[17];
  const float* W2 = (const float*)d_in[18];
  const float* as2 = (const float*)d_in[19];
  const float* ad2 = (const float*)d_in[20];
  const float* b2 = (const float*)d_in[21];
  float* out = (float*)d_out;

  const int N = NNODES, E = NEDGES;
  char* p = (char*)d_ws;
  auto alloc = [&](size_t bytes) {
    void* r = (void*)p;
    p += (bytes + 255) & ~(size_t)255;
    return r;
  };
  float* buf_h = (float*)alloc((size_t)N * 256 * 4);
  float* buf_x = (float*)alloc((size_t)N * 256 * 4);
  float* a_s = (float*)alloc((size_t)N * 4 * 4);
  float* a_d = (float*)alloc((size_t)N * 4 * 4);
  unsigned* mkey = (unsigned*)alloc((size_t)N * 4 * 4);
  float* ssum = (float*)alloc((size_t)N * 4 * 4);
  int* counts = (int*)alloc((size_t)N * 4);
  int* row_ptr = (int*)alloc((size_t)(N + 1) * 4);
  int* cursor = (int*)alloc((size_t)N * 4);
  int* srcs = (int*)alloc((size_t)NTOT * 4);

  int nb256 = (N + 255) / 256;
  int eb256 = (E + 255) / 256;
  int tb256 = (NTOT + 255) / 256;

  // CSR build (once; reused across layers)
  init_counts_kernel<<<nb256, 256, 0, stream>>>(counts, N);
  hist_kernel<<<eb256, 256, 0, stream>>>(ei, counts);
  scan_kernel<<<1, 256, 0, stream>>>(counts, row_ptr, cursor, N);
  scatter_kernel<<<tb256, 256, 0, stream>>>(ei, cursor, srcs);

  dim3 gemm_block(256);
  // ---- layer 0: x[N,128] @ W0[128,256] ----
  {
    dim3 grid((N + 63) / 64, 4);
    gemm_kernel<<<grid, gemm_block, 0, stream>>>(x, W0, buf_h, N, 128, 256);
    att_kernel<4><<<N, 256, 0, stream>>>(buf_h, as0, ad0, a_s, a_d, N);
    init_ms_kernel<<<(N * 4 + 255) / 256, 256, 0, stream>>>(mkey, ssum, N * 4);
    edge_max_kernel<4><<<tb256, 256, 0, stream>>>(ei, a_s, a_d, mkey);
    edge_sum_kernel<4><<<tb256, 256, 0, stream>>>(ei, a_s, a_d, mkey, ssum);
    aggregate_kernel<<<N, 256, 0, stream>>>(buf_h, a_s, a_d, mkey, ssum, row_ptr, srcs,
                                            b0, g0p, be0, m0p, v0p, buf_x, N);
  }
  // ---- layer 1: buf_x[N,256] @ W1[256,256] ----
  {
    dim3 grid((N + 63) / 64, 4);
    gemm_kernel<<<grid, gemm_block, 0, stream>>>(buf_x, W1, buf_h, N, 256, 256);
    att_kernel<4><<<N, 256, 0, stream>>>(buf_h, as1, ad1, a_s, a_d, N);
    init_ms_kernel<<<(N * 4 + 255) / 256, 256, 0, stream>>>(mkey, ssum, N * 4);
    edge_max_kernel<4><<<tb256, 256, 0, stream>>>(ei, a_s, a_d, mkey);
    edge_sum_kernel<4><<<tb256, 256, 0, stream>>>(ei, a_s, a_d, mkey, ssum);
    aggregate_kernel<<<N, 256, 0, stream>>>(buf_h, a_s, a_d, mkey, ssum, row_ptr, srcs,
                                            b1, g1p, be1, m1p, v1p, buf_x, N);
  }
  // ---- layer 2: buf_x[N,256] @ W2[256,64], H=1, log_softmax ----
  {
    dim3 grid((N + 63) / 64, 1);
    gemm_kernel<<<grid, gemm_block, 0, stream>>>(buf_x, W2, buf_h, N, 256, 64);
    att_kernel<1><<<N, 64, 0, stream>>>(buf_h, as2, ad2, a_s, a_d, N);
    init_ms_kernel<<<nb256, 256, 0, stream>>>(mkey, ssum, N);
    edge_max_kernel<1><<<tb256, 256, 0, stream>>>(ei, a_s, a_d, mkey);
    edge_sum_kernel<1><<<tb256, 256, 0, stream>>>(ei, a_s, a_d, mkey, ssum);
    aggregate2_kernel<<<(N + 3) / 4, 256, 0, stream>>>(buf_h, a_s, a_d, mkey, ssum,
                                                       row_ptr, srcs, b2, out, N);
  }
}

// Round 2
// 444.981 us; speedup vs baseline: 1.7082x; 1.7082x over previous
//
#include <hip/hip_runtime.h>
#include <cstdint>
#include <cstddef>

#define NNODES 10000
#define NEDGES 320000
#define NTOT   (NEDGES + NNODES)

__device__ __forceinline__ float lrelu(float x) { return x > 0.f ? x : 0.2f * x; }

// ---------- GEMM: C[N,M] = A[N,K] @ B[K,M] ----------
__global__ __launch_bounds__(256) void gemm_kernel(
    const float* __restrict__ A, const float* __restrict__ B, float* __restrict__ C,
    int N, int K, int M) {
  __shared__ float As[8][68];
  __shared__ float Bs[8][68];
  int tid = threadIdx.x;
  int n0 = blockIdx.x * 64;
  int m0 = blockIdx.y * 64;
  int tx = tid & 15, ty = tid >> 4;
  float acc[4][4] = {{0.f}};
  int an = tid >> 2;
  int ak = (tid & 3) << 1;
  int bk = tid >> 5;
  int bm = (tid & 31) << 1;
  const float* Arow = A + (size_t)(n0 + an) * K;
  bool avalid = (n0 + an) < N;
  for (int k0 = 0; k0 < K; k0 += 8) {
    float a0 = 0.f, a1 = 0.f;
    if (avalid) { a0 = Arow[k0 + ak]; a1 = Arow[k0 + ak + 1]; }
    As[ak][an] = a0; As[ak + 1][an] = a1;
    const float* Bp = B + (size_t)(k0 + bk) * M + m0 + bm;
    Bs[bk][bm] = Bp[0]; Bs[bk][bm + 1] = Bp[1];
    __syncthreads();
#pragma unroll
    for (int kk = 0; kk < 8; ++kk) {
      float4 a4 = *(const float4*)&As[kk][ty << 2];
      float4 b4 = *(const float4*)&Bs[kk][tx << 2];
      float av[4] = {a4.x, a4.y, a4.z, a4.w};
      float bv[4] = {b4.x, b4.y, b4.z, b4.w};
#pragma unroll
      for (int i = 0; i < 4; ++i)
#pragma unroll
        for (int j = 0; j < 4; ++j)
          acc[i][j] = fmaf(av[i], bv[j], acc[i][j]);
    }
    __syncthreads();
  }
#pragma unroll
  for (int i = 0; i < 4; ++i) {
    int n = n0 + (ty << 2) + i;
    if (n < N) {
      float4 o = make_float4(acc[i][0], acc[i][1], acc[i][2], acc[i][3]);
      *(float4*)&C[(size_t)n * M + m0 + (tx << 2)] = o;
    }
  }
}

// ---------- attention coefficients: a_s[n,h]=dot(h[n,h,:],att_src[h,:]) ----------
template <int H>
__global__ void att_kernel(const float* __restrict__ hbuf, const float* __restrict__ atts,
                           const float* __restrict__ attd, float* __restrict__ a_s,
                           float* __restrict__ a_d, int N) {
  int n = blockIdx.x;
  int w = threadIdx.x >> 6;
  int c = threadIdx.x & 63;
  float v = hbuf[(size_t)n * (H * 64) + w * 64 + c];
  float ps = v * atts[w * 64 + c];
  float pd = v * attd[w * 64 + c];
#pragma unroll
  for (int off = 32; off; off >>= 1) {
    ps += __shfl_xor(ps, off);
    pd += __shfl_xor(pd, off);
  }
  if (c == 0) { a_s[n * H + w] = ps; a_d[n * H + w] = pd; }
}

// ---------- CSR build ----------
__global__ void init_counts_kernel(int* __restrict__ counts, int N) {
  int i = blockIdx.x * 256 + threadIdx.x;
  if (i < N) counts[i] = 1;  // self loop
}
__global__ void hist_kernel(const int* __restrict__ ei, int* __restrict__ counts) {
  int e = blockIdx.x * 256 + threadIdx.x;
  if (e < NEDGES) atomicAdd(&counts[ei[NEDGES + e]], 1);
}

// single-block scan over counts -> row_ptr (exclusive), cursor copy
__global__ void scan_kernel(const int* __restrict__ counts, int* __restrict__ row_ptr,
                            int* __restrict__ cursor, int N) {
  __shared__ int part[256];
  int t = threadIdx.x;
  int chunk = (N + 255) >> 8;
  int base = t * chunk;
  int s = 0;
  for (int i = 0; i < chunk; ++i) {
    int idx = base + i;
    if (idx < N) s += counts[idx];
  }
  part[t] = s;
  __syncthreads();
  for (int off = 1; off < 256; off <<= 1) {
    int v = (t >= off) ? part[t - off] : 0;
    __syncthreads();
    part[t] += v;
    __syncthreads();
  }
  int run = part[t] - s;  // exclusive prefix
  for (int i = 0; i < chunk; ++i) {
    int idx = base + i;
    if (idx < N) {
      row_ptr[idx] = run;
      cursor[idx] = run;
      run += counts[idx];
    }
  }
  if (t == 255) row_ptr[N] = part[255];
}

__global__ void scatter_kernel(const int* __restrict__ ei, int* __restrict__ cursor,
                               int* __restrict__ srcs) {
  int e = blockIdx.x * 256 + threadIdx.x;
  if (e < NEDGES) {
    int s = ei[e], d = ei[NEDGES + e];
    srcs[atomicAdd(&cursor[d], 1)] = s;
  } else if (e < NTOT) {
    int nn = e - NEDGES;
    srcs[atomicAdd(&cursor[nn], 1)] = nn;
  }
}

// ---------- fused aggregation, layers 0/1 (H=4, C=64): softmax stats + gather + bias+ELU+BN ----------
__global__ __launch_bounds__(256) void aggregate_kernel(
    const float* __restrict__ hbuf, const float* __restrict__ a_s, const float* __restrict__ a_d,
    const int* __restrict__ row_ptr, const int* __restrict__ srcs,
    const float* __restrict__ bias, const float* __restrict__ gam, const float* __restrict__ bet,
    const float* __restrict__ rmean, const float* __restrict__ rvar,
    float* __restrict__ xout, int N) {
  int n = blockIdx.x;
  int hh = threadIdx.x >> 6;
  int c = threadIdx.x & 63;
  int jb = row_ptr[n], je = row_ptr[n + 1];
  float adn = a_d[n * 4 + hh];

  // --- softmax stats across the row, wave-cooperative (64 lanes per head) ---
  float mx = -1e30f;
  for (int j = jb + c; j < je; j += 64)
    mx = fmaxf(mx, lrelu(a_s[srcs[j] * 4 + hh] + adn));
#pragma unroll
  for (int off = 32; off; off >>= 1) mx = fmaxf(mx, __shfl_xor(mx, off));
  float sum = 0.f;
  for (int j = jb + c; j < je; j += 64)
    sum += __expf(lrelu(a_s[srcs[j] * 4 + hh] + adn) - mx);
#pragma unroll
  for (int off = 32; off; off >>= 1) sum += __shfl_xor(sum, off);
  float inv = 1.0f / (sum + 1e-16f);

  // --- weighted gather ---
  float acc = 0.f;
  for (int j = jb; j < je; ++j) {
    int s = srcs[j];
    float alpha = __expf(lrelu(a_s[s * 4 + hh] + adn) - mx) * inv;
    acc = fmaf(alpha, hbuf[(size_t)s * 256 + hh * 64 + c], acc);
  }
  int col = hh * 64 + c;
  float v = acc + bias[col];
  v = v > 0.f ? v : (__expf(v) - 1.f);  // ELU
  v = fmaf(gam[col] * (v - rmean[col]), rsqrtf(rvar[col] + 1e-5f), bet[col]);
  xout[(size_t)n * 256 + col] = v;
}

// ---------- fused aggregation layer 2 (H=1, C=64) + bias + log_softmax ----------
__global__ __launch_bounds__(256) void aggregate2_kernel(
    const float* __restrict__ hbuf, const float* __restrict__ a_s, const float* __restrict__ a_d,
    const int* __restrict__ row_ptr, const int* __restrict__ srcs,
    const float* __restrict__ bias, float* __restrict__ out, int N) {
  int n = blockIdx.x * 4 + (threadIdx.x >> 6);
  int c = threadIdx.x & 63;
  if (n >= N) return;
  int jb = row_ptr[n], je = row_ptr[n + 1];
  float adn = a_d[n];

  float mx = -1e30f;
  for (int j = jb + c; j < je; j += 64)
    mx = fmaxf(mx, lrelu(a_s[srcs[j]] + adn));
#pragma unroll
  for (int off = 32; off; off >>= 1) mx = fmaxf(mx, __shfl_xor(mx, off));
  float sum = 0.f;
  for (int j = jb + c; j < je; j += 64)
    sum += __expf(lrelu(a_s[srcs[j]] + adn) - mx);
#pragma unroll
  for (int off = 32; off; off >>= 1) sum += __shfl_xor(sum, off);
  float inv = 1.0f / (sum + 1e-16f);

  float acc = 0.f;
  for (int j = jb; j < je; ++j) {
    int s = srcs[j];
    float alpha = __expf(lrelu(a_s[s] + adn) - mx) * inv;
    acc = fmaf(alpha, hbuf[(size_t)s * 64 + c], acc);
  }
  float v = acc + bias[c];
  float vmx = v;
#pragma unroll
  for (int off = 32; off; off >>= 1) vmx = fmaxf(vmx, __shfl_xor(vmx, off));
  float ex = __expf(v - vmx);
#pragma unroll
  for (int off = 32; off; off >>= 1) ex += __shfl_xor(ex, off);
  out[(size_t)n * 64 + c] = (v - vmx) - logf(ex);
}

// ---------- host ----------
extern "C" void kernel_launch(void* const* d_in, const int* in_sizes, int n_in,
                              void* d_out, int out_size, void* d_ws, size_t ws_size,
                              hipStream_t stream) {
  const float* x = (const float*)d_in[0];
  const int* ei = (const int*)d_in[1];
  const float* W0 = (const float*)d_in[2];
  const float* as0 = (const float*)d_in[3];
  const float* ad0 = (const float*)d_in[4];
  const float* b0 = (const float*)d_in[5];
  const float* g0p = (const float*)d_in[6];
  const float* be0 = (const float*)d_in[7];
  const float* m0p = (const float*)d_in[8];
  const float* v0p = (const float*)d_in[9];
  const float* W1 = (const float*)d_in[10];
  const float* as1 = (const float*)d_in[11];
  const float* ad1 = (const float*)d_in[12];
  const float* b1 = (const float*)d_in[13];
  const float* g1p = (const float*)d_in[14];
  const float* be1 = (const float*)d_in[15];
  const float* m1p = (const float*)d_in[16];
  const float* v1p = (const float*)d_in[17];
  const float* W2 = (const float*)d_in[18];
  const float* as2 = (const float*)d_in[19];
  const float* ad2 = (const float*)d_in[20];
  const float* b2 = (const float*)d_in[21];
  float* out = (float*)d_out;

  const int N = NNODES, E = NEDGES;
  char* p = (char*)d_ws;
  auto alloc = [&](size_t bytes) {
    void* r = (void*)p;
    p += (bytes + 255) & ~(size_t)255;
    return r;
  };
  float* buf_h = (float*)alloc((size_t)N * 256 * 4);
  float* buf_x = (float*)alloc((size_t)N * 256 * 4);
  float* a_s = (float*)alloc((size_t)N * 4 * 4);
  float* a_d = (float*)alloc((size_t)N * 4 * 4);
  int* counts = (int*)alloc((size_t)N * 4);
  int* row_ptr = (int*)alloc((size_t)(N + 1) * 4);
  int* cursor = (int*)alloc((size_t)N * 4);
  int* srcs = (int*)alloc((size_t)NTOT * 4);

  int nb256 = (N + 255) / 256;
  int eb256 = (E + 255) / 256;
  int tb256 = (NTOT + 255) / 256;

  // CSR build (once; reused across layers)
  init_counts_kernel<<<nb256, 256, 0, stream>>>(counts, N);
  hist_kernel<<<eb256, 256, 0, stream>>>(ei, counts);
  scan_kernel<<<1, 256, 0, stream>>>(counts, row_ptr, cursor, N);
  scatter_kernel<<<tb256, 256, 0, stream>>>(ei, cursor, srcs);

  dim3 gemm_block(256);
  // ---- layer 0: x[N,128] @ W0[128,256] ----
  {
    dim3 grid((N + 63) / 64, 4);
    gemm_kernel<<<grid, gemm_block, 0, stream>>>(x, W0, buf_h, N, 128, 256);
    att_kernel<4><<<N, 256, 0, stream>>>(buf_h, as0, ad0, a_s, a_d, N);
    aggregate_kernel<<<N, 256, 0, stream>>>(buf_h, a_s, a_d, row_ptr, srcs,
                                            b0, g0p, be0, m0p, v0p, buf_x, N);
  }
  // ---- layer 1: buf_x[N,256] @ W1[256,256] ----
  {
    dim3 grid((N + 63) / 64, 4);
    gemm_kernel<<<grid, gemm_block, 0, stream>>>(buf_x, W1, buf_h, N, 256, 256);
    att_kernel<4><<<N, 256, 0, stream>>>(buf_h, as1, ad1, a_s, a_d, N);
    aggregate_kernel<<<N, 256, 0, stream>>>(buf_h, a_s, a_d, row_ptr, srcs,
                                            b1, g1p, be1, m1p, v1p, buf_x, N);
  }
  // ---- layer 2: buf_x[N,256] @ W2[256,64], H=1, log_softmax ----
  {
    dim3 grid((N + 63) / 64, 1);
    gemm_kernel<<<grid, gemm_block, 0, stream>>>(buf_x, W2, buf_h, N, 256, 64);
    att_kernel<1><<<N, 64, 0, stream>>>(buf_h, as2, ad2, a_s, a_d, N);
    aggregate2_kernel<<<(N + 3) / 4, 256, 0, stream>>>(buf_h, a_s, a_d,
                                                       row_ptr, srcs, b2, out, N);
  }
}

// Round 3
// 333.633 us; speedup vs baseline: 2.2784x; 1.3337x over previous
//
#include <hip/hip_runtime.h>
#include <cstdint>
#include <cstddef>

#define NNODES 10000
#define NEDGES 320000
#define NTOT   (NEDGES + NNODES)

typedef unsigned short ushort_t;

__device__ __forceinline__ float lrelu(float x) { return x > 0.f ? x : 0.2f * x; }
__device__ __forceinline__ float b2f(ushort_t u) { return __uint_as_float(((unsigned)u) << 16); }
__device__ __forceinline__ ushort_t f2b(float v) {
  unsigned b = __float_as_uint(v);
  b += 0x7fffu + ((b >> 16) & 1u);  // RNE
  return (ushort_t)(b >> 16);
}
__device__ __forceinline__ float bcast_f(float v, int lane) {
  return __uint_as_float(__builtin_amdgcn_readlane(__float_as_uint(v), lane));
}
__device__ __forceinline__ int bcast_i(int v, int lane) {
  return __builtin_amdgcn_readlane(v, lane);
}

// ---------- GEMM: C[N,M] = A[N,K] @ B[K,M] ----------
__global__ __launch_bounds__(256) void gemm_kernel(
    const float* __restrict__ A, const float* __restrict__ B, float* __restrict__ C,
    int N, int K, int M) {
  __shared__ float As[8][68];
  __shared__ float Bs[8][68];
  int tid = threadIdx.x;
  int n0 = blockIdx.x * 64;
  int m0 = blockIdx.y * 64;
  int tx = tid & 15, ty = tid >> 4;
  float acc[4][4] = {{0.f}};
  int an = tid >> 2;
  int ak = (tid & 3) << 1;
  int bk = tid >> 5;
  int bm = (tid & 31) << 1;
  const float* Arow = A + (size_t)(n0 + an) * K;
  bool avalid = (n0 + an) < N;
  for (int k0 = 0; k0 < K; k0 += 8) {
    float a0 = 0.f, a1 = 0.f;
    if (avalid) { a0 = Arow[k0 + ak]; a1 = Arow[k0 + ak + 1]; }
    As[ak][an] = a0; As[ak + 1][an] = a1;
    const float* Bp = B + (size_t)(k0 + bk) * M + m0 + bm;
    Bs[bk][bm] = Bp[0]; Bs[bk][bm + 1] = Bp[1];
    __syncthreads();
#pragma unroll
    for (int kk = 0; kk < 8; ++kk) {
      float4 a4 = *(const float4*)&As[kk][ty << 2];
      float4 b4 = *(const float4*)&Bs[kk][tx << 2];
      float av[4] = {a4.x, a4.y, a4.z, a4.w};
      float bv[4] = {b4.x, b4.y, b4.z, b4.w};
#pragma unroll
      for (int i = 0; i < 4; ++i)
#pragma unroll
        for (int j = 0; j < 4; ++j)
          acc[i][j] = fmaf(av[i], bv[j], acc[i][j]);
    }
    __syncthreads();
  }
#pragma unroll
  for (int i = 0; i < 4; ++i) {
    int n = n0 + (ty << 2) + i;
    if (n < N) {
      float4 o = make_float4(acc[i][0], acc[i][1], acc[i][2], acc[i][3]);
      *(float4*)&C[(size_t)n * M + m0 + (tx << 2)] = o;
    }
  }
}

// ---------- attention coefficients + bf16 copy of h ----------
template <int H>
__global__ void att_kernel(const float* __restrict__ hbuf, const float* __restrict__ atts,
                           const float* __restrict__ attd, float* __restrict__ a_s,
                           float* __restrict__ a_d, ushort_t* __restrict__ hb16, int N) {
  int n = blockIdx.x;
  int w = threadIdx.x >> 6;
  int c = threadIdx.x & 63;
  float v = hbuf[(size_t)n * (H * 64) + w * 64 + c];
  hb16[(size_t)n * (H * 64) + w * 64 + c] = f2b(v);
  float ps = v * atts[w * 64 + c];
  float pd = v * attd[w * 64 + c];
#pragma unroll
  for (int off = 32; off; off >>= 1) {
    ps += __shfl_xor(ps, off);
    pd += __shfl_xor(pd, off);
  }
  if (c == 0) { a_s[n * H + w] = ps; a_d[n * H + w] = pd; }
}

// ---------- CSR build ----------
__global__ void init_counts_kernel(int* __restrict__ counts, int N) {
  int i = blockIdx.x * 256 + threadIdx.x;
  if (i < N) counts[i] = 1;  // self loop
}
__global__ void hist_kernel(const int* __restrict__ ei, int* __restrict__ counts) {
  int e = blockIdx.x * 256 + threadIdx.x;
  if (e < NEDGES) atomicAdd(&counts[ei[NEDGES + e]], 1);
}

__global__ void scan_kernel(const int* __restrict__ counts, int* __restrict__ row_ptr,
                            int* __restrict__ cursor, int N) {
  __shared__ int part[256];
  int t = threadIdx.x;
  int chunk = (N + 255) >> 8;
  int base = t * chunk;
  int s = 0;
  for (int i = 0; i < chunk; ++i) {
    int idx = base + i;
    if (idx < N) s += counts[idx];
  }
  part[t] = s;
  __syncthreads();
  for (int off = 1; off < 256; off <<= 1) {
    int v = (t >= off) ? part[t - off] : 0;
    __syncthreads();
    part[t] += v;
    __syncthreads();
  }
  int run = part[t] - s;  // exclusive prefix
  for (int i = 0; i < chunk; ++i) {
    int idx = base + i;
    if (idx < N) {
      row_ptr[idx] = run;
      cursor[idx] = run;
      run += counts[idx];
    }
  }
  if (t == 255) row_ptr[N] = part[255];
}

__global__ void scatter_kernel(const int* __restrict__ ei, int* __restrict__ cursor,
                               int* __restrict__ srcs) {
  int e = blockIdx.x * 256 + threadIdx.x;
  if (e < NEDGES) {
    int s = ei[e], d = ei[NEDGES + e];
    srcs[atomicAdd(&cursor[d], 1)] = s;
  } else if (e < NTOT) {
    int nn = e - NEDGES;
    srcs[atomicAdd(&cursor[nn], 1)] = nn;
  }
}

// ---------- fused aggregation, layers 0/1 (H=4, C=64) ----------
__global__ __launch_bounds__(256) void aggregate_kernel(
    const ushort_t* __restrict__ hb16, const float* __restrict__ a_s,
    const float* __restrict__ a_d,
    const int* __restrict__ row_ptr, const int* __restrict__ srcs,
    const float* __restrict__ bias, const float* __restrict__ gam, const float* __restrict__ bet,
    const float* __restrict__ rmean, const float* __restrict__ rvar,
    float* __restrict__ xout, int N) {
  int n = blockIdx.x;
  int hh = threadIdx.x >> 6;
  int c = threadIdx.x & 63;
  int jb = row_ptr[n], je = row_ptr[n + 1];
  int deg = je - jb;
  float adn = a_d[n * 4 + hh];
  const char* hbase = (const char*)hb16 + hh * 128 + c * 2;
  float acc = 0.f;

  if (deg <= 64) {
    // one edge per lane: stats + alpha in registers, SGPR-broadcast gather
    int s = (c < deg) ? srcs[jb + c] : 0;
    float l = (c < deg) ? lrelu(a_s[s * 4 + hh] + adn) : -1e30f;
    float mx = l;
#pragma unroll
    for (int off = 32; off; off >>= 1) mx = fmaxf(mx, __shfl_xor(mx, off));
    float e = (c < deg) ? __expf(l - mx) : 0.f;
    float sum = e;
#pragma unroll
    for (int off = 32; off; off >>= 1) sum += __shfl_xor(sum, off);
    float alpha = e / (sum + 1e-16f);
    int offb = s * 512;  // bf16 row stride = 256*2 bytes
    int t = 0;
    for (; t + 4 <= deg; t += 4) {
      float a0 = bcast_f(alpha, t), a1 = bcast_f(alpha, t + 1);
      float a2 = bcast_f(alpha, t + 2), a3 = bcast_f(alpha, t + 3);
      int o0 = bcast_i(offb, t), o1 = bcast_i(offb, t + 1);
      int o2 = bcast_i(offb, t + 2), o3 = bcast_i(offb, t + 3);
      ushort_t u0 = *(const ushort_t*)(hbase + o0);
      ushort_t u1 = *(const ushort_t*)(hbase + o1);
      ushort_t u2 = *(const ushort_t*)(hbase + o2);
      ushort_t u3 = *(const ushort_t*)(hbase + o3);
      acc = fmaf(a0, b2f(u0), acc);
      acc = fmaf(a1, b2f(u1), acc);
      acc = fmaf(a2, b2f(u2), acc);
      acc = fmaf(a3, b2f(u3), acc);
    }
    for (; t < deg; ++t)
      acc = fmaf(bcast_f(alpha, t), b2f(*(const ushort_t*)(hbase + bcast_i(offb, t))), acc);
  } else {
    // generic fallback (rare): two-pass stats + chunked broadcast gather
    float mx = -1e30f;
    for (int j = jb + c; j < je; j += 64)
      mx = fmaxf(mx, lrelu(a_s[srcs[j] * 4 + hh] + adn));
#pragma unroll
    for (int off = 32; off; off >>= 1) mx = fmaxf(mx, __shfl_xor(mx, off));
    float sum = 0.f;
    for (int j = jb + c; j < je; j += 64)
      sum += __expf(lrelu(a_s[srcs[j] * 4 + hh] + adn) - mx);
#pragma unroll
    for (int off = 32; off; off >>= 1) sum += __shfl_xor(sum, off);
    float inv = 1.0f / (sum + 1e-16f);
    for (int j0 = jb; j0 < je; j0 += 64) {
      int cnt = min(64, je - j0);
      int s = (c < cnt) ? srcs[j0 + c] : 0;
      float alpha = (c < cnt) ? __expf(lrelu(a_s[s * 4 + hh] + adn) - mx) * inv : 0.f;
      int offb = s * 512;
      for (int t = 0; t < cnt; ++t)
        acc = fmaf(bcast_f(alpha, t), b2f(*(const ushort_t*)(hbase + bcast_i(offb, t))), acc);
    }
  }

  int col = hh * 64 + c;
  float v = acc + bias[col];
  v = v > 0.f ? v : (__expf(v) - 1.f);  // ELU
  v = fmaf(gam[col] * (v - rmean[col]), rsqrtf(rvar[col] + 1e-5f), bet[col]);
  xout[(size_t)n * 256 + col] = v;
}

// ---------- fused aggregation layer 2 (H=1, C=64) + bias + log_softmax ----------
__global__ __launch_bounds__(256) void aggregate2_kernel(
    const ushort_t* __restrict__ hb16, const float* __restrict__ a_s,
    const float* __restrict__ a_d,
    const int* __restrict__ row_ptr, const int* __restrict__ srcs,
    const float* __restrict__ bias, float* __restrict__ out, int N) {
  int n = blockIdx.x * 4 + (threadIdx.x >> 6);
  int c = threadIdx.x & 63;
  if (n >= N) return;
  int jb = row_ptr[n], je = row_ptr[n + 1];
  int deg = je - jb;
  float adn = a_d[n];
  const char* hbase = (const char*)hb16 + c * 2;
  float acc = 0.f;

  if (deg <= 64) {
    int s = (c < deg) ? srcs[jb + c] : 0;
    float l = (c < deg) ? lrelu(a_s[s] + adn) : -1e30f;
    float mx = l;
#pragma unroll
    for (int off = 32; off; off >>= 1) mx = fmaxf(mx, __shfl_xor(mx, off));
    float e = (c < deg) ? __expf(l - mx) : 0.f;
    float sum = e;
#pragma unroll
    for (int off = 32; off; off >>= 1) sum += __shfl_xor(sum, off);
    float alpha = e / (sum + 1e-16f);
    int offb = s * 128;  // bf16 row stride = 64*2 bytes
    int t = 0;
    for (; t + 4 <= deg; t += 4) {
      float a0 = bcast_f(alpha, t), a1 = bcast_f(alpha, t + 1);
      float a2 = bcast_f(alpha, t + 2), a3 = bcast_f(alpha, t + 3);
      int o0 = bcast_i(offb, t), o1 = bcast_i(offb, t + 1);
      int o2 = bcast_i(offb, t + 2), o3 = bcast_i(offb, t + 3);
      ushort_t u0 = *(const ushort_t*)(hbase + o0);
      ushort_t u1 = *(const ushort_t*)(hbase + o1);
      ushort_t u2 = *(const ushort_t*)(hbase + o2);
      ushort_t u3 = *(const ushort_t*)(hbase + o3);
      acc = fmaf(a0, b2f(u0), acc);
      acc = fmaf(a1, b2f(u1), acc);
      acc = fmaf(a2, b2f(u2), acc);
      acc = fmaf(a3, b2f(u3), acc);
    }
    for (; t < deg; ++t)
      acc = fmaf(bcast_f(alpha, t), b2f(*(const ushort_t*)(hbase + bcast_i(offb, t))), acc);
  } else {
    float mx = -1e30f;
    for (int j = jb + c; j < je; j += 64)
      mx = fmaxf(mx, lrelu(a_s[srcs[j]] + adn));
#pragma unroll
    for (int off = 32; off; off >>= 1) mx = fmaxf(mx, __shfl_xor(mx, off));
    float sum = 0.f;
    for (int j = jb + c; j < je; j += 64)
      sum += __expf(lrelu(a_s[srcs[j]] + adn) - mx);
#pragma unroll
    for (int off = 32; off; off >>= 1) sum += __shfl_xor(sum, off);
    float inv = 1.0f / (sum + 1e-16f);
    for (int j0 = jb; j0 < je; j0 += 64) {
      int cnt = min(64, je - j0);
      int s = (c < cnt) ? srcs[j0 + c] : 0;
      float alpha = (c < cnt) ? __expf(lrelu(a_s[s] + adn) - mx) * inv : 0.f;
      int offb = s * 128;
      for (int t = 0; t < cnt; ++t)
        acc = fmaf(bcast_f(alpha, t), b2f(*(const ushort_t*)(hbase + bcast_i(offb, t))), acc);
    }
  }

  float v = acc + bias[c];
  float vmx = v;
#pragma unroll
  for (int off = 32; off; off >>= 1) vmx = fmaxf(vmx, __shfl_xor(vmx, off));
  float ex = __expf(v - vmx);
#pragma unroll
  for (int off = 32; off; off >>= 1) ex += __shfl_xor(ex, off);
  out[(size_t)n * 64 + c] = (v - vmx) - logf(ex);
}

// ---------- host ----------
extern "C" void kernel_launch(void* const* d_in, const int* in_sizes, int n_in,
                              void* d_out, int out_size, void* d_ws, size_t ws_size,
                              hipStream_t stream) {
  const float* x = (const float*)d_in[0];
  const int* ei = (const int*)d_in[1];
  const float* W0 = (const float*)d_in[2];
  const float* as0 = (const float*)d_in[3];
  const float* ad0 = (const float*)d_in[4];
  const float* b0 = (const float*)d_in[5];
  const float* g0p = (const float*)d_in[6];
  const float* be0 = (const float*)d_in[7];
  const float* m0p = (const float*)d_in[8];
  const float* v0p = (const float*)d_in[9];
  const float* W1 = (const float*)d_in[10];
  const float* as1 = (const float*)d_in[11];
  const float* ad1 = (const float*)d_in[12];
  const float* b1 = (const float*)d_in[13];
  const float* g1p = (const float*)d_in[14];
  const float* be1 = (const float*)d_in[15];
  const float* m1p = (const float*)d_in[16];
  const float* v1p = (const float*)d_in[17];
  const float* W2 = (const float*)d_in[18];
  const float* as2 = (const float*)d_in[19];
  const float* ad2 = (const float*)d_in[20];
  const float* b2 = (const float*)d_in[21];
  float* out = (float*)d_out;

  const int N = NNODES, E = NEDGES;
  char* p = (char*)d_ws;
  auto alloc = [&](size_t bytes) {
    void* r = (void*)p;
    p += (bytes + 255) & ~(size_t)255;
    return r;
  };
  float* buf_h = (float*)alloc((size_t)N * 256 * 4);
  float* buf_x = (float*)alloc((size_t)N * 256 * 4);
  ushort_t* hb16 = (ushort_t*)alloc((size_t)N * 256 * 2);
  float* a_s = (float*)alloc((size_t)N * 4 * 4);
  float* a_d = (float*)alloc((size_t)N * 4 * 4);
  int* counts = (int*)alloc((size_t)N * 4);
  int* row_ptr = (int*)alloc((size_t)(N + 1) * 4);
  int* cursor = (int*)alloc((size_t)N * 4);
  int* srcs = (int*)alloc((size_t)NTOT * 4);

  int nb256 = (N + 255) / 256;
  int eb256 = (E + 255) / 256;
  int tb256 = (NTOT + 255) / 256;

  // CSR build (once; reused across layers)
  init_counts_kernel<<<nb256, 256, 0, stream>>>(counts, N);
  hist_kernel<<<eb256, 256, 0, stream>>>(ei, counts);
  scan_kernel<<<1, 256, 0, stream>>>(counts, row_ptr, cursor, N);
  scatter_kernel<<<tb256, 256, 0, stream>>>(ei, cursor, srcs);

  dim3 gemm_block(256);
  // ---- layer 0: x[N,128] @ W0[128,256] ----
  {
    dim3 grid((N + 63) / 64, 4);
    gemm_kernel<<<grid, gemm_block, 0, stream>>>(x, W0, buf_h, N, 128, 256);
    att_kernel<4><<<N, 256, 0, stream>>>(buf_h, as0, ad0, a_s, a_d, hb16, N);
    aggregate_kernel<<<N, 256, 0, stream>>>(hb16, a_s, a_d, row_ptr, srcs,
                                            b0, g0p, be0, m0p, v0p, buf_x, N);
  }
  // ---- layer 1: buf_x[N,256] @ W1[256,256] ----
  {
    dim3 grid((N + 63) / 64, 4);
    gemm_kernel<<<grid, gemm_block, 0, stream>>>(buf_x, W1, buf_h, N, 256, 256);
    att_kernel<4><<<N, 256, 0, stream>>>(buf_h, as1, ad1, a_s, a_d, hb16, N);
    aggregate_kernel<<<N, 256, 0, stream>>>(hb16, a_s, a_d, row_ptr, srcs,
                                            b1, g1p, be1, m1p, v1p, buf_x, N);
  }
  // ---- layer 2: buf_x[N,256] @ W2[256,64], H=1, log_softmax ----
  {
    dim3 grid((N + 63) / 64, 1);
    gemm_kernel<<<grid, gemm_block, 0, stream>>>(buf_x, W2, buf_h, N, 256, 64);
    att_kernel<1><<<N, 64, 0, stream>>>(buf_h, as2, ad2, a_s, a_d, hb16, N);
    aggregate2_kernel<<<(N + 3) / 4, 256, 0, stream>>>(hb16, a_s, a_d,
                                                       row_ptr, srcs, b2, out, N);
  }
}

// Round 4
// 296.057 us; speedup vs baseline: 2.5675x; 1.1269x over previous
//
#include <hip/hip_runtime.h>
#include <cstdint>
#include <cstddef>

#define NNODES 10000
#define NEDGES 320000
#define NTOT   (NEDGES + NNODES)
#define NPAD   10048  // 157*64

typedef unsigned short ushort_t;
typedef short bf16x8 __attribute__((ext_vector_type(8)));
typedef float f32x4 __attribute__((ext_vector_type(4)));

__device__ __forceinline__ float lrelu(float x) { return x > 0.f ? x : 0.2f * x; }
__device__ __forceinline__ float b2f(ushort_t u) { return __uint_as_float(((unsigned)u) << 16); }
__device__ __forceinline__ ushort_t f2b(float v) {
  unsigned b = __float_as_uint(v);
  b += 0x7fffu + ((b >> 16) & 1u);  // RNE
  return (ushort_t)(b >> 16);
}
__device__ __forceinline__ float bcast_f(float v, int lane) {
  return __uint_as_float(__builtin_amdgcn_readlane(__float_as_uint(v), lane));
}
__device__ __forceinline__ int bcast_i(int v, int lane) {
  return __builtin_amdgcn_readlane(v, lane);
}

// ---------- f32 -> bf16 elementwise ----------
__global__ void conv_kernel(const float* __restrict__ A, ushort_t* __restrict__ B, int n) {
  int i = blockIdx.x * 256 + threadIdx.x;
  if (i < n) B[i] = f2b(A[i]);
}

// ---------- W[K,M] f32 -> WT[M,K] bf16 ----------
__global__ void convT_kernel(const float* __restrict__ W, ushort_t* __restrict__ WT, int K, int M) {
  int i = blockIdx.x * 256 + threadIdx.x;
  if (i < K * M) {
    int k = i / M, m = i - k * M;
    WT[(size_t)m * K + k] = f2b(W[i]);
  }
}

// ---------- fused MFMA GEMM + attention coefficients ----------
// h[n, m0+c] = sum_k Ab[n,k] * WT[m0+c,k]; writes hb16 (bf16) and a_s/a_d for head=blockIdx.y.
// No LDS: A-frag and B-frag are contiguous 16B global loads (WT pre-transposed).
template <int K, int H>
__global__ __launch_bounds__(256) void gemm_att_kernel(
    const ushort_t* __restrict__ Ab,   // [NPAD, K] bf16
    const ushort_t* __restrict__ WT,   // [H*64, K] bf16
    const float* __restrict__ atts, const float* __restrict__ attd,  // [H*64]
    ushort_t* __restrict__ hb16,       // [N, H*64] bf16
    float* __restrict__ a_s, float* __restrict__ a_d,                // [N*H]
    int N) {
  int tid = threadIdx.x;
  int wave = tid >> 6, lane = tid & 63;
  int quad = lane >> 4, l16 = lane & 15;
  int n0 = blockIdx.x * 64;
  int head = blockIdx.y;
  int m0 = head * 64;
  const int M = H * 64;

  f32x4 acc[4];
#pragma unroll
  for (int t = 0; t < 4; ++t) acc[t] = (f32x4){0.f, 0.f, 0.f, 0.f};

  const ushort_t* Ap = Ab + (size_t)(n0 + wave * 16 + l16) * K + quad * 8;
  const ushort_t* Wp = WT + (size_t)(m0 + l16) * K + quad * 8;

  for (int k0 = 0; k0 < K; k0 += 32) {
    bf16x8 af = *(const bf16x8*)(Ap + k0);
#pragma unroll
    for (int t = 0; t < 4; ++t) {
      bf16x8 bf = *(const bf16x8*)(Wp + (size_t)t * 16 * K + k0);
      acc[t] = __builtin_amdgcn_mfma_f32_16x16x32_bf16(af, bf, acc[t], 0, 0, 0);
    }
  }

  // epilogue: store bf16 h, reduce a_s/a_d per row (all 64 head-cols live in this block)
#pragma unroll
  for (int reg = 0; reg < 4; ++reg) {
    int r = n0 + wave * 16 + quad * 4 + reg;
    float ps = 0.f, pd = 0.f;
#pragma unroll
    for (int t = 0; t < 4; ++t) {
      float v = acc[t][reg];
      int col = m0 + t * 16 + l16;
      ps = fmaf(v, atts[col], ps);
      pd = fmaf(v, attd[col], pd);
      if (r < N) hb16[(size_t)r * M + col] = f2b(v);
    }
#pragma unroll
    for (int off = 8; off; off >>= 1) {
      ps += __shfl_xor(ps, off);
      pd += __shfl_xor(pd, off);
    }
    if (l16 == 0 && r < N) {
      a_s[r * H + head] = ps;
      a_d[r * H + head] = pd;
    }
  }
}

// ---------- CSR build ----------
__global__ void init_counts_kernel(int* __restrict__ counts, int N) {
  int i = blockIdx.x * 256 + threadIdx.x;
  if (i < N) counts[i] = 1;  // self loop
}
__global__ void hist_kernel(const int* __restrict__ ei, int* __restrict__ counts) {
  int e = blockIdx.x * 256 + threadIdx.x;
  if (e < NEDGES) atomicAdd(&counts[ei[NEDGES + e]], 1);
}

__global__ void scan_kernel(const int* __restrict__ counts, int* __restrict__ row_ptr,
                            int* __restrict__ cursor, int N) {
  __shared__ int part[256];
  int t = threadIdx.x;
  int chunk = (N + 255) >> 8;
  int base = t * chunk;
  int s = 0;
  for (int i = 0; i < chunk; ++i) {
    int idx = base + i;
    if (idx < N) s += counts[idx];
  }
  part[t] = s;
  __syncthreads();
  for (int off = 1; off < 256; off <<= 1) {
    int v = (t >= off) ? part[t - off] : 0;
    __syncthreads();
    part[t] += v;
    __syncthreads();
  }
  int run = part[t] - s;  // exclusive prefix
  for (int i = 0; i < chunk; ++i) {
    int idx = base + i;
    if (idx < N) {
      row_ptr[idx] = run;
      cursor[idx] = run;
      run += counts[idx];
    }
  }
  if (t == 255) row_ptr[N] = part[255];
}

__global__ void scatter_kernel(const int* __restrict__ ei, int* __restrict__ cursor,
                               int* __restrict__ srcs) {
  int e = blockIdx.x * 256 + threadIdx.x;
  if (e < NEDGES) {
    int s = ei[e], d = ei[NEDGES + e];
    srcs[atomicAdd(&cursor[d], 1)] = s;
  } else if (e < NTOT) {
    int nn = e - NEDGES;
    srcs[atomicAdd(&cursor[nn], 1)] = nn;
  }
}

// ---------- fused aggregation, layers 0/1 (H=4, C=64): softmax + gather + bias+ELU+BN ----------
__global__ __launch_bounds__(256) void aggregate_kernel(
    const ushort_t* __restrict__ hb16, const float* __restrict__ a_s,
    const float* __restrict__ a_d,
    const int* __restrict__ row_ptr, const int* __restrict__ srcs,
    const float* __restrict__ bias, const float* __restrict__ gam, const float* __restrict__ bet,
    const float* __restrict__ rmean, const float* __restrict__ rvar,
    ushort_t* __restrict__ xb16, int N) {
  int n = blockIdx.x;
  int hh = threadIdx.x >> 6;
  int c = threadIdx.x & 63;
  int jb = row_ptr[n], je = row_ptr[n + 1];
  int deg = je - jb;
  float adn = a_d[n * 4 + hh];
  const char* hbase = (const char*)hb16 + hh * 128 + c * 2;
  float acc = 0.f;

  if (deg <= 64) {
    int s = (c < deg) ? srcs[jb + c] : 0;
    float l = (c < deg) ? lrelu(a_s[s * 4 + hh] + adn) : -1e30f;
    float mx = l;
#pragma unroll
    for (int off = 32; off; off >>= 1) mx = fmaxf(mx, __shfl_xor(mx, off));
    float e = (c < deg) ? __expf(l - mx) : 0.f;
    float sum = e;
#pragma unroll
    for (int off = 32; off; off >>= 1) sum += __shfl_xor(sum, off);
    float alpha = e / (sum + 1e-16f);
    int offb = s * 512;
    int t = 0;
    for (; t + 4 <= deg; t += 4) {
      float a0 = bcast_f(alpha, t), a1 = bcast_f(alpha, t + 1);
      float a2 = bcast_f(alpha, t + 2), a3 = bcast_f(alpha, t + 3);
      int o0 = bcast_i(offb, t), o1 = bcast_i(offb, t + 1);
      int o2 = bcast_i(offb, t + 2), o3 = bcast_i(offb, t + 3);
      ushort_t u0 = *(const ushort_t*)(hbase + o0);
      ushort_t u1 = *(const ushort_t*)(hbase + o1);
      ushort_t u2 = *(const ushort_t*)(hbase + o2);
      ushort_t u3 = *(const ushort_t*)(hbase + o3);
      acc = fmaf(a0, b2f(u0), acc);
      acc = fmaf(a1, b2f(u1), acc);
      acc = fmaf(a2, b2f(u2), acc);
      acc = fmaf(a3, b2f(u3), acc);
    }
    for (; t < deg; ++t)
      acc = fmaf(bcast_f(alpha, t), b2f(*(const ushort_t*)(hbase + bcast_i(offb, t))), acc);
  } else {
    float mx = -1e30f;
    for (int j = jb + c; j < je; j += 64)
      mx = fmaxf(mx, lrelu(a_s[srcs[j] * 4 + hh] + adn));
#pragma unroll
    for (int off = 32; off; off >>= 1) mx = fmaxf(mx, __shfl_xor(mx, off));
    float sum = 0.f;
    for (int j = jb + c; j < je; j += 64)
      sum += __expf(lrelu(a_s[srcs[j] * 4 + hh] + adn) - mx);
#pragma unroll
    for (int off = 32; off; off >>= 1) sum += __shfl_xor(sum, off);
    float inv = 1.0f / (sum + 1e-16f);
    for (int j0 = jb; j0 < je; j0 += 64) {
      int cnt = min(64, je - j0);
      int s = (c < cnt) ? srcs[j0 + c] : 0;
      float alpha = (c < cnt) ? __expf(lrelu(a_s[s * 4 + hh] + adn) - mx) * inv : 0.f;
      int offb = s * 512;
      for (int t = 0; t < cnt; ++t)
        acc = fmaf(bcast_f(alpha, t), b2f(*(const ushort_t*)(hbase + bcast_i(offb, t))), acc);
    }
  }

  int col = hh * 64 + c;
  float v = acc + bias[col];
  v = v > 0.f ? v : (__expf(v) - 1.f);  // ELU
  v = fmaf(gam[col] * (v - rmean[col]), rsqrtf(rvar[col] + 1e-5f), bet[col]);
  xb16[(size_t)n * 256 + col] = f2b(v);
}

// ---------- fused aggregation layer 2 (H=1, C=64) + bias + log_softmax ----------
__global__ __launch_bounds__(256) void aggregate2_kernel(
    const ushort_t* __restrict__ hb16, const float* __restrict__ a_s,
    const float* __restrict__ a_d,
    const int* __restrict__ row_ptr, const int* __restrict__ srcs,
    const float* __restrict__ bias, float* __restrict__ out, int N) {
  int n = blockIdx.x * 4 + (threadIdx.x >> 6);
  int c = threadIdx.x & 63;
  if (n >= N) return;
  int jb = row_ptr[n], je = row_ptr[n + 1];
  int deg = je - jb;
  float adn = a_d[n];
  const char* hbase = (const char*)hb16 + c * 2;
  float acc = 0.f;

  if (deg <= 64) {
    int s = (c < deg) ? srcs[jb + c] : 0;
    float l = (c < deg) ? lrelu(a_s[s] + adn) : -1e30f;
    float mx = l;
#pragma unroll
    for (int off = 32; off; off >>= 1) mx = fmaxf(mx, __shfl_xor(mx, off));
    float e = (c < deg) ? __expf(l - mx) : 0.f;
    float sum = e;
#pragma unroll
    for (int off = 32; off; off >>= 1) sum += __shfl_xor(sum, off);
    float alpha = e / (sum + 1e-16f);
    int offb = s * 128;
    int t = 0;
    for (; t + 4 <= deg; t += 4) {
      float a0 = bcast_f(alpha, t), a1 = bcast_f(alpha, t + 1);
      float a2 = bcast_f(alpha, t + 2), a3 = bcast_f(alpha, t + 3);
      int o0 = bcast_i(offb, t), o1 = bcast_i(offb, t + 1);
      int o2 = bcast_i(offb, t + 2), o3 = bcast_i(offb, t + 3);
      ushort_t u0 = *(const ushort_t*)(hbase + o0);
      ushort_t u1 = *(const ushort_t*)(hbase + o1);
      ushort_t u2 = *(const ushort_t*)(hbase + o2);
      ushort_t u3 = *(const ushort_t*)(hbase + o3);
      acc = fmaf(a0, b2f(u0), acc);
      acc = fmaf(a1, b2f(u1), acc);
      acc = fmaf(a2, b2f(u2), acc);
      acc = fmaf(a3, b2f(u3), acc);
    }
    for (; t < deg; ++t)
      acc = fmaf(bcast_f(alpha, t), b2f(*(const ushort_t*)(hbase + bcast_i(offb, t))), acc);
  } else {
    float mx = -1e30f;
    for (int j = jb + c; j < je; j += 64)
      mx = fmaxf(mx, lrelu(a_s[srcs[j]] + adn));
#pragma unroll
    for (int off = 32; off; off >>= 1) mx = fmaxf(mx, __shfl_xor(mx, off));
    float sum = 0.f;
    for (int j = jb + c; j < je; j += 64)
      sum += __expf(lrelu(a_s[srcs[j]] + adn) - mx);
#pragma unroll
    for (int off = 32; off; off >>= 1) sum += __shfl_xor(sum, off);
    float inv = 1.0f / (sum + 1e-16f);
    for (int j0 = jb; j0 < je; j0 += 64) {
      int cnt = min(64, je - j0);
      int s = (c < cnt) ? srcs[j0 + c] : 0;
      float alpha = (c < cnt) ? __expf(lrelu(a_s[s] + adn) - mx) * inv : 0.f;
      int offb = s * 128;
      for (int t = 0; t < cnt; ++t)
        acc = fmaf(bcast_f(alpha, t), b2f(*(const ushort_t*)(hbase + bcast_i(offb, t))), acc);
    }
  }

  float v = acc + bias[c];
  float vmx = v;
#pragma unroll
  for (int off = 32; off; off >>= 1) vmx = fmaxf(vmx, __shfl_xor(vmx, off));
  float ex = __expf(v - vmx);
#pragma unroll
  for (int off = 32; off; off >>= 1) ex += __shfl_xor(ex, off);
  out[(size_t)n * 64 + c] = (v - vmx) - logf(ex);
}

// ---------- host ----------
extern "C" void kernel_launch(void* const* d_in, const int* in_sizes, int n_in,
                              void* d_out, int out_size, void* d_ws, size_t ws_size,
                              hipStream_t stream) {
  const float* x = (const float*)d_in[0];
  const int* ei = (const int*)d_in[1];
  const float* W0 = (const float*)d_in[2];
  const float* as0 = (const float*)d_in[3];
  const float* ad0 = (const float*)d_in[4];
  const float* b0 = (const float*)d_in[5];
  const float* g0p = (const float*)d_in[6];
  const float* be0 = (const float*)d_in[7];
  const float* m0p = (const float*)d_in[8];
  const float* v0p = (const float*)d_in[9];
  const float* W1 = (const float*)d_in[10];
  const float* as1 = (const float*)d_in[11];
  const float* ad1 = (const float*)d_in[12];
  const float* b1 = (const float*)d_in[13];
  const float* g1p = (const float*)d_in[14];
  const float* be1 = (const float*)d_in[15];
  const float* m1p = (const float*)d_in[16];
  const float* v1p = (const float*)d_in[17];
  const float* W2 = (const float*)d_in[18];
  const float* as2 = (const float*)d_in[19];
  const float* ad2 = (const float*)d_in[20];
  const float* b2 = (const float*)d_in[21];
  float* out = (float*)d_out;

  const int N = NNODES, E = NEDGES;
  char* p = (char*)d_ws;
  auto alloc = [&](size_t bytes) {
    void* r = (void*)p;
    p += (bytes + 255) & ~(size_t)255;
    return r;
  };
  ushort_t* xb0 = (ushort_t*)alloc((size_t)NPAD * 128 * 2);   // layer-0 input, bf16
  ushort_t* xb16 = (ushort_t*)alloc((size_t)NPAD * 256 * 2);  // layer-1/2 input, bf16
  ushort_t* hb16 = (ushort_t*)alloc((size_t)N * 256 * 2);     // per-layer h, bf16
  ushort_t* WT0 = (ushort_t*)alloc((size_t)256 * 128 * 2);
  ushort_t* WT1 = (ushort_t*)alloc((size_t)256 * 256 * 2);
  ushort_t* WT2 = (ushort_t*)alloc((size_t)64 * 256 * 2);
  float* a_s = (float*)alloc((size_t)N * 4 * 4);
  float* a_d = (float*)alloc((size_t)N * 4 * 4);
  int* counts = (int*)alloc((size_t)N * 4);
  int* row_ptr = (int*)alloc((size_t)(N + 1) * 4);
  int* cursor = (int*)alloc((size_t)N * 4);
  int* srcs = (int*)alloc((size_t)NTOT * 4);

  int nb256 = (N + 255) / 256;
  int eb256 = (E + 255) / 256;
  int tb256 = (NTOT + 255) / 256;

  // input conversions
  conv_kernel<<<(N * 128 + 255) / 256, 256, 0, stream>>>(x, xb0, N * 128);
  convT_kernel<<<(128 * 256 + 255) / 256, 256, 0, stream>>>(W0, WT0, 128, 256);
  convT_kernel<<<(256 * 256 + 255) / 256, 256, 0, stream>>>(W1, WT1, 256, 256);
  convT_kernel<<<(256 * 64 + 255) / 256, 256, 0, stream>>>(W2, WT2, 256, 64);

  // CSR build (once; reused across layers)
  init_counts_kernel<<<nb256, 256, 0, stream>>>(counts, N);
  hist_kernel<<<eb256, 256, 0, stream>>>(ei, counts);
  scan_kernel<<<1, 256, 0, stream>>>(counts, row_ptr, cursor, N);
  scatter_kernel<<<tb256, 256, 0, stream>>>(ei, cursor, srcs);

  dim3 gblk(256);
  // ---- layer 0 ----
  gemm_att_kernel<128, 4><<<dim3(NPAD / 64, 4), gblk, 0, stream>>>(
      xb0, WT0, as0, ad0, hb16, a_s, a_d, N);
  aggregate_kernel<<<N, 256, 0, stream>>>(hb16, a_s, a_d, row_ptr, srcs,
                                          b0, g0p, be0, m0p, v0p, xb16, N);
  // ---- layer 1 ----
  gemm_att_kernel<256, 4><<<dim3(NPAD / 64, 4), gblk, 0, stream>>>(
      xb16, WT1, as1, ad1, hb16, a_s, a_d, N);
  aggregate_kernel<<<N, 256, 0, stream>>>(hb16, a_s, a_d, row_ptr, srcs,
                                          b1, g1p, be1, m1p, v1p, xb16, N);
  // ---- layer 2 ----
  gemm_att_kernel<256, 1><<<dim3(NPAD / 64, 1), gblk, 0, stream>>>(
      xb16, WT2, as2, ad2, hb16, a_s, a_d, N);
  aggregate2_kernel<<<(N + 3) / 4, 256, 0, stream>>>(hb16, a_s, a_d,
                                                     row_ptr, srcs, b2, out, N);
}